// Round 9
// baseline (487.199 us; speedup 1.0000x reference)
//
#include <hip/hip_runtime.h>
#include <hip/hip_bf16.h>
#include <cstdint>
#include <cstddef>

// Problem constants
#define NB_B 8
#define NL   64
#define NT   512
#define CF   128
#define HD   128
#define NK   10
#define NE   1024
#define NBLK 1024u

// d_out flat offsets (fp32 elements)
static constexpr size_t P_TOT    = (size_t)NB_B * NL * NT;     // 262144
static constexpr size_t PI_OFF   = 0;
static constexpr size_t SIG_OFF  = P_TOT * 10;
static constexpr size_t MU_OFF   = SIG_OFF + P_TOT * 10;
static constexpr size_t DIST_OFF = MU_OFF + P_TOT * 10;
static constexpr size_t AT_OFF   = DIST_OFF + P_TOT;
static constexpr size_t BD_OFF   = AT_OFF + 512 * 28;
static constexpr size_t CB_OFF   = BD_OFF + NE * 6;

typedef __attribute__((ext_vector_type(8))) short short8;
typedef __attribute__((ext_vector_type(4))) float floatx4;
typedef __attribute__((ext_vector_type(2))) float floatx2;

union U8 { short8 s8; unsigned int u[4]; };

__device__ __forceinline__ float bf2f(unsigned short u) {
    return __uint_as_float(((unsigned int)u) << 16);
}
__device__ __forceinline__ unsigned short f2bf(float f) {
    unsigned int x = __float_as_uint(f);
    x = (x + 0x7FFFu + ((x >> 16) & 1u)) >> 16;   // RNE
    return (unsigned short)x;
}
// HW packed f32x2 -> bf16x2 (v_cvt_pk_bf16_f32 on gfx950); a -> low 16.
__device__ __forceinline__ unsigned int pk2bf(float a, float b) {
    __hip_bfloat162 h = __float22bfloat162_rn(make_float2(a, b));
    return *reinterpret_cast<unsigned int*>(&h);
}
// Branchless exact ELU: max(x,0) + (exp(min(x,0)) - 1)
__device__ __forceinline__ float elu(float x) {
    return fmaxf(x, 0.f) + (__expf(fminf(x, 0.f)) - 1.f);
}

// ---------------------------------------------------------------------------
// ONE plain dispatch, 1024 blocks x 256 threads. __launch_bounds__(256,4)
// => VGPR<=128, LDS 17.4KB => 4 blocks/CU guaranteed => grid == resident
// capacity (4 x 256 CU) => software grid barrier is deadlock-free.
// Phase 1 (blocks 0..288): zl'(32 blk) / zt'(256 blk) 16-row MFMA tiles,
//   wcomb_t (1 blk).   [software grid barrier on ws counter]
// Phase 2: persistent loop u = blk, blk+1024 (+2048+blk for blk<12):
//   u in [0,2048): main path per (b,l,chunk); [2048,2052): atom_types;
//   [2052,2060): bond_types.  All bodies identical to R7 (validated).
// ---------------------------------------------------------------------------
__global__ __launch_bounds__(256, 4) void k_all(
    const float* __restrict__ hl,
    const float* __restrict__ ht,
    const float* __restrict__ hlpos,
    const float* __restrict__ htpos,
    const int*   __restrict__ eidx,
    const float* __restrict__ W1,
    const float* __restrict__ b1,
    const float* __restrict__ gamma_,
    const float* __restrict__ beta_,
    const float* __restrict__ rmean,
    const float* __restrict__ rvar,
    const float* __restrict__ Wpi,
    const float* __restrict__ bpi,
    const float* __restrict__ Wsig,
    const float* __restrict__ bsig,
    const float* __restrict__ Wmu,
    const float* __restrict__ bmu,
    const float* __restrict__ Wat,
    const float* __restrict__ bat,
    const float* __restrict__ Wbd,
    const float* __restrict__ bbd,
    unsigned short* __restrict__ zl,
    unsigned short* __restrict__ zt,
    unsigned short* __restrict__ wcomb_t,
    unsigned int*   __restrict__ cnt,
    float* __restrict__ out)
{
    __shared__ float Dl[128 * 34];   // 17408 B, stride 34 => <=2-way banks
    __shared__ float biass[32];
    __shared__ float pls[3];

    const int blk0 = blockIdx.x;
    const int tid  = threadIdx.x;
    const int lane = tid & 63;
    const int wave = tid >> 6;
    const int m    = lane & 15;
    const int quad = lane >> 4;

    // ================= Phase 1: producers (16-row tiles) =================
    if (blk0 < 288) {
        const bool is_l = (blk0 < 32);
        const int rbase = is_l ? blk0 * 16 : (blk0 - 32) * 16;
        const float* A  = is_l ? hl : ht;
        const float* Wx = W1 + (is_l ? 0 : (size_t)CF * HD);   // [128 c][128 h]
        unsigned short* Z = is_l ? zl : zt;
        const int n0 = wave * 32 + m;

        floatx4 acc[2];
        acc[0] = (floatx4){0.f, 0.f, 0.f, 0.f};
        acc[1] = (floatx4){0.f, 0.f, 0.f, 0.f};

        #pragma unroll
        for (int kb = 0; kb < 4; ++kb) {
            const int k0 = kb * 32 + quad * 8;
            const float* ap = A + (size_t)(rbase + m) * CF + k0;
            const float4 f0 = *(const float4*)ap;
            const float4 f1 = *(const float4*)(ap + 4);
            U8 t;
            t.u[0] = pk2bf(f0.x, f0.y);
            t.u[1] = pk2bf(f0.z, f0.w);
            t.u[2] = pk2bf(f1.x, f1.y);
            t.u[3] = pk2bf(f1.z, f1.w);
            const short8 a = t.s8;

            short8 bf[2];
            #pragma unroll
            for (int nt = 0; nt < 2; ++nt) {
                const int n = n0 + nt * 16;
                float w[8];
                #pragma unroll
                for (int j = 0; j < 8; ++j)
                    w[j] = Wx[(size_t)(k0 + j) * HD + n];
                U8 tt;
                #pragma unroll
                for (int j = 0; j < 4; ++j) tt.u[j] = pk2bf(w[2*j], w[2*j+1]);
                bf[nt] = tt.s8;
            }
            #pragma unroll
            for (int nt = 0; nt < 2; ++nt)
                acc[nt] = __builtin_amdgcn_mfma_f32_16x16x32_bf16(a, bf[nt], acc[nt], 0, 0, 0);
        }

        #pragma unroll
        for (int nt = 0; nt < 2; ++nt) {
            const int col = n0 + nt * 16;
            const float s   = gamma_[col] * rsqrtf(rvar[col] + 1e-4f);
            const float off = is_l ? 0.f : ((b1[col] - rmean[col]) * s + beta_[col]);
            #pragma unroll
            for (int r = 0; r < 4; ++r) {
                const int row = rbase + quad * 4 + r;
                Z[(size_t)row * HD + col] = f2bf(acc[nt][r] * s + off);
            }
        }
    } else if (blk0 == 288) {
        for (int i = tid; i < 32 * HD; i += 256) {
            const int n = i >> 7, k = i & 127;
            float v = 0.f;
            if (n < 10)      v = Wpi [k * NK + n];
            else if (n < 20) v = Wsig[k * NK + (n - 10)];
            else if (n < 30) v = Wmu [k * NK + (n - 20)];
            wcomb_t[i] = f2bf(v);
        }
    }

    // ================= software grid barrier =================
    __threadfence();
    __syncthreads();
    if (tid == 0) {
        __hip_atomic_fetch_add(cnt, 1u, __ATOMIC_ACQ_REL, __HIP_MEMORY_SCOPE_AGENT);
        unsigned int v;
        do {
            v = __hip_atomic_load(cnt, __ATOMIC_ACQUIRE, __HIP_MEMORY_SCOPE_AGENT);
            if (v >= NBLK) break;
            __builtin_amdgcn_s_sleep(2);
        } while (true);
    }
    __syncthreads();
    __threadfence();

    // ================= Phase 2: consumers =================
    for (int u = blk0; u < 2060; u += 1024) {
        if (u >= 2048) {
            const int ab = u - 2048;
            if (ab < 4) {
                // ---- atom_types: rows ab*128 + wave*32 .. +31 ----
                const int rbase = ab * 128 + wave * 32;
                floatx4 acc[2][2];
                #pragma unroll
                for (int i = 0; i < 2; ++i)
                    #pragma unroll
                    for (int j = 0; j < 2; ++j)
                        acc[i][j] = (floatx4){0.f, 0.f, 0.f, 0.f};
                #pragma unroll
                for (int kb = 0; kb < 4; ++kb) {
                    const int k0 = kb * 32 + quad * 8;
                    short8 a[2];
                    #pragma unroll
                    for (int mt = 0; mt < 2; ++mt) {
                        const float* ap = hl + (size_t)(rbase + mt * 16 + m) * CF + k0;
                        const float4 f0 = *(const float4*)ap;
                        const float4 f1 = *(const float4*)(ap + 4);
                        U8 t;
                        t.u[0] = pk2bf(f0.x, f0.y);
                        t.u[1] = pk2bf(f0.z, f0.w);
                        t.u[2] = pk2bf(f1.x, f1.y);
                        t.u[3] = pk2bf(f1.z, f1.w);
                        a[mt] = t.s8;
                    }
                    short8 bf[2];
                    #pragma unroll
                    for (int nt = 0; nt < 2; ++nt) {
                        const int n = nt * 16 + m;
                        const int nc = (n < 28) ? n : 0;
                        #pragma unroll
                        for (int j = 0; j < 8; ++j) {
                            const float w = Wat[(size_t)(k0 + j) * 28 + nc];
                            bf[nt][j] = (short)f2bf((n < 28) ? w : 0.f);
                        }
                    }
                    #pragma unroll
                    for (int mt = 0; mt < 2; ++mt)
                        #pragma unroll
                        for (int nt = 0; nt < 2; ++nt)
                            acc[mt][nt] = __builtin_amdgcn_mfma_f32_16x16x32_bf16(a[mt], bf[nt], acc[mt][nt], 0, 0, 0);
                }
                #pragma unroll
                for (int nt = 0; nt < 2; ++nt) {
                    const int col = nt * 16 + m;
                    if (col < 28) {
                        const float bias = bat[col];
                        #pragma unroll
                        for (int mt = 0; mt < 2; ++mt)
                            #pragma unroll
                            for (int r = 0; r < 4; ++r) {
                                const int row = rbase + mt * 16 + quad * 4 + r;
                                out[AT_OFF + (size_t)row * 28 + col] = acc[mt][nt][r] + bias;
                            }
                    }
                }
            } else {
                // ---- bond_types: rows (ab-4)*128 + wave*32 .. +31, K=256 ----
                const int rbase = (ab - 4) * 128 + wave * 32;
                const int e0 = rbase + m, e1 = rbase + 16 + m;
                const int s00 = eidx[e0], s01 = eidx[NE + e0];
                const int s10 = eidx[e1], s11 = eidx[NE + e1];
                floatx4 acc[2];
                acc[0] = (floatx4){0.f, 0.f, 0.f, 0.f};
                acc[1] = (floatx4){0.f, 0.f, 0.f, 0.f};
                const int nc = (m < 6) ? m : 0;
                #pragma unroll
                for (int kb = 0; kb < 8; ++kb) {
                    const int k0 = kb * 32 + quad * 8;
                    const bool lo = (k0 < 128);
                    const int off = lo ? k0 : (k0 - 128);
                    short8 a[2];
                    #pragma unroll
                    for (int mt = 0; mt < 2; ++mt) {
                        const int src = lo ? (mt ? s10 : s00) : (mt ? s11 : s01);
                        const float* ap = hl + (size_t)src * CF + off;
                        const float4 f0 = *(const float4*)ap;
                        const float4 f1 = *(const float4*)(ap + 4);
                        U8 t;
                        t.u[0] = pk2bf(f0.x, f0.y);
                        t.u[1] = pk2bf(f0.z, f0.w);
                        t.u[2] = pk2bf(f1.x, f1.y);
                        t.u[3] = pk2bf(f1.z, f1.w);
                        a[mt] = t.s8;
                    }
                    short8 bf;
                    #pragma unroll
                    for (int j = 0; j < 8; ++j) {
                        const float w = Wbd[(size_t)(k0 + j) * 6 + nc];
                        bf[j] = (short)f2bf((m < 6) ? w : 0.f);
                    }
                    acc[0] = __builtin_amdgcn_mfma_f32_16x16x32_bf16(a[0], bf, acc[0], 0, 0, 0);
                    acc[1] = __builtin_amdgcn_mfma_f32_16x16x32_bf16(a[1], bf, acc[1], 0, 0, 0);
                }
                if (m < 6) {
                    const float bias = bbd[m];
                    #pragma unroll
                    for (int mt = 0; mt < 2; ++mt)
                        #pragma unroll
                        for (int r = 0; r < 4; ++r) {
                            const int row = rbase + mt * 16 + quad * 4 + r;
                            out[BD_OFF + (size_t)row * 6 + m] = acc[mt][r] + bias;
                        }
                }
            }
            continue;
        }

        const int b  = u >> 8;
        const int l  = (u >> 2) & 63;
        const int ch = u & 3;

        if (tid < 32) {
            float v = 0.f;
            if (tid < 10)      v = bpi[tid];
            else if (tid < 20) v = bsig[tid - 10];
            else if (tid < 30) v = bmu[tid - 20];
            biass[tid] = v;
        } else if (tid < 35) {
            pls[tid - 32] = hlpos[(size_t)(b * NL + l) * 3 + (tid - 32)];
        }

        // B fragments: single 16B loads from transposed head weights
        short8 bfrag[2][4];
        #pragma unroll
        for (int nt = 0; nt < 2; ++nt)
            #pragma unroll
            for (int kb = 0; kb < 4; ++kb)
                bfrag[nt][kb] = *(const short8*)(wcomb_t + (size_t)(nt * 16 + m) * HD + kb * 32 + quad * 8);

        // ---- stage A: direct A-frag compute + MFMA ----
        const unsigned short* zlr = zl + (size_t)(b * NL + l) * HD;
        const unsigned short* ztb = zt + (size_t)(b * NT + ch * 128) * HD;

        floatx4 acc[2][2];
        #pragma unroll
        for (int i = 0; i < 2; ++i)
            #pragma unroll
            for (int j = 0; j < 2; ++j)
                acc[i][j] = (floatx4){0.f, 0.f, 0.f, 0.f};

        #pragma unroll
        for (int kb = 0; kb < 4; ++kb) {
            const int k0 = kb * 32 + quad * 8;
            const short8 zlv = *(const short8*)(zlr + k0);
            float zf[8];
            #pragma unroll
            for (int j = 0; j < 8; ++j) zf[j] = bf2f((unsigned short)zlv[j]);

            short8 a[2];
            #pragma unroll
            for (int mt = 0; mt < 2; ++mt) {
                const int row = wave * 32 + mt * 16 + m;
                const short8 ztv = *(const short8*)(ztb + (size_t)row * HD + k0);
                float e[8];
                #pragma unroll
                for (int j = 0; j < 8; ++j)
                    e[j] = elu(zf[j] + bf2f((unsigned short)ztv[j]));
                U8 t;
                #pragma unroll
                for (int j = 0; j < 4; ++j) t.u[j] = pk2bf(e[2*j], e[2*j+1]);
                a[mt] = t.s8;
            }
            #pragma unroll
            for (int mt = 0; mt < 2; ++mt)
                #pragma unroll
                for (int nt = 0; nt < 2; ++nt)
                    acc[mt][nt] = __builtin_amdgcn_mfma_f32_16x16x32_bf16(a[mt], bfrag[nt][kb], acc[mt][nt], 0, 0, 0);
        }

        // D: col = lane&15, row = quad*4 + r   [validated R3/R4]
        #pragma unroll
        for (int mt = 0; mt < 2; ++mt)
            #pragma unroll
            for (int nt = 0; nt < 2; ++nt)
                #pragma unroll
                for (int r = 0; r < 4; ++r) {
                    const int row = wave * 32 + mt * 16 + quad * 4 + r;
                    const int col = nt * 16 + m;
                    Dl[row * 34 + col] = acc[mt][nt][r];
                }
        __syncthreads();

        // ---- stage B: epilogues (fp32 stores) ----
        const size_t gp = ((size_t)(b * NL + l)) * NT + ch * 128 + (tid & 127);
        if (tid < 128) {
            const int p = tid;
            float v[10];
            float mx = -1e30f;
            #pragma unroll
            for (int n = 0; n < 10; ++n) {
                v[n] = Dl[p * 34 + n] + biass[n];
                mx = fmaxf(mx, v[n]);
            }
            float s = 0.f;
            #pragma unroll
            for (int n = 0; n < 10; ++n) { v[n] = __expf(v[n] - mx); s += v[n]; }
            const float inv = 1.f / s;
            floatx2* po = (floatx2*)(out + PI_OFF + gp * 10);
            #pragma unroll
            for (int n = 0; n < 5; ++n) po[n] = (floatx2){v[2*n] * inv, v[2*n+1] * inv};
        } else {
            const int p = tid - 128;
            float sg[10], mv[10];
            #pragma unroll
            for (int n = 0; n < 10; ++n) {
                sg[n] = elu(Dl[p * 34 + 10 + n] + biass[10 + n]) + 1.1f;
                mv[n] = elu(Dl[p * 34 + 20 + n] + biass[20 + n]) + 1.0f;
            }
            floatx2* ps = (floatx2*)(out + SIG_OFF + gp * 10);
            floatx2* pm = (floatx2*)(out + MU_OFF  + gp * 10);
            #pragma unroll
            for (int n = 0; n < 5; ++n) {
                ps[n] = (floatx2){sg[2*n], sg[2*n+1]};
                pm[n] = (floatx2){mv[2*n], mv[2*n+1]};
            }
            const int t = ch * 128 + p;
            const size_t pb = (size_t)(b * NT + t) * 3;
            const float dx = pls[0] - htpos[pb + 0];
            const float dy = pls[1] - htpos[pb + 1];
            const float dz = pls[2] - htpos[pb + 2];
            out[DIST_OFF + gp] = sqrtf(dx * dx + dy * dy + dz * dz);
            out[CB_OFF + gp]   = (float)b;
        }
        __syncthreads();   // Dl/biass reads done before next unit overwrites
    }
}

// ---------------------------------------------------------------------------
extern "C" void kernel_launch(void* const* d_in, const int* in_sizes, int n_in,
                              void* d_out, int out_size, void* d_ws, size_t ws_size,
                              hipStream_t stream)
{
    const float* hl     = (const float*)d_in[0];
    const float* ht     = (const float*)d_in[1];
    const float* hlpos  = (const float*)d_in[2];
    const float* htpos  = (const float*)d_in[3];
    const int*   eidx   = (const int*)d_in[4];
    const float* W1     = (const float*)d_in[5];
    const float* b1     = (const float*)d_in[6];
    const float* gamma_ = (const float*)d_in[7];
    const float* beta_  = (const float*)d_in[8];
    const float* rmean  = (const float*)d_in[9];
    const float* rvar   = (const float*)d_in[10];
    const float* Wpi    = (const float*)d_in[11];
    const float* bpi    = (const float*)d_in[12];
    const float* Wsig   = (const float*)d_in[13];
    const float* bsig   = (const float*)d_in[14];
    const float* Wmu    = (const float*)d_in[15];
    const float* bmu    = (const float*)d_in[16];
    const float* Wat    = (const float*)d_in[17];
    const float* bat    = (const float*)d_in[18];
    const float* Wbd    = (const float*)d_in[19];
    const float* bbd    = (const float*)d_in[20];

    float* out = (float*)d_out;
    unsigned char* wsb  = (unsigned char*)d_ws;
    unsigned short* zl      = (unsigned short*)wsb;                 // 131072 B
    unsigned short* zt      = (unsigned short*)(wsb + 131072);      // 1048576 B
    unsigned short* wcomb_t = (unsigned short*)(wsb + 1179648);     // 8192 B
    unsigned int*   cnt     = (unsigned int*)  (wsb + 1187840);     // 4 B

    hipMemsetAsync(cnt, 0, 4, stream);
    k_all<<<1024, 256, 0, stream>>>(hl, ht, hlpos, htpos, eidx,
                                    W1, b1, gamma_, beta_, rmean, rvar,
                                    Wpi, bpi, Wsig, bsig, Wmu, bmu,
                                    Wat, bat, Wbd, bbd,
                                    zl, zt, wcomb_t, cnt, out);
}

// Round 10
// 133.269 us; speedup vs baseline: 3.6558x; 3.6558x over previous
//
#include <hip/hip_runtime.h>
#include <hip/hip_bf16.h>
#include <cstdint>
#include <cstddef>

// Problem constants
#define NB_B 8
#define NL   64
#define NT   512
#define CF   128
#define HD   128
#define NK   10
#define NE   1024

// d_out flat offsets (fp32 elements)
static constexpr size_t P_TOT    = (size_t)NB_B * NL * NT;     // 262144
static constexpr size_t PI_OFF   = 0;
static constexpr size_t SIG_OFF  = P_TOT * 10;
static constexpr size_t MU_OFF   = SIG_OFF + P_TOT * 10;
static constexpr size_t DIST_OFF = MU_OFF + P_TOT * 10;
static constexpr size_t AT_OFF   = DIST_OFF + P_TOT;
static constexpr size_t BD_OFF   = AT_OFF + 512 * 28;
static constexpr size_t CB_OFF   = BD_OFF + NE * 6;

typedef __attribute__((ext_vector_type(8))) short short8;
typedef __attribute__((ext_vector_type(4))) float floatx4;
typedef __attribute__((ext_vector_type(2))) float floatx2;

union U8 { short8 s8; unsigned int u[4]; };

__device__ __forceinline__ float bf2f(unsigned short u) {
    return __uint_as_float(((unsigned int)u) << 16);
}
__device__ __forceinline__ unsigned short f2bf(float f) {
    unsigned int x = __float_as_uint(f);
    x = (x + 0x7FFFu + ((x >> 16) & 1u)) >> 16;   // RNE
    return (unsigned short)x;
}
// HW packed f32x2 -> bf16x2 (v_cvt_pk_bf16_f32 on gfx950); a -> low 16.
__device__ __forceinline__ unsigned int pk2bf(float a, float b) {
    __hip_bfloat162 h = __float22bfloat162_rn(make_float2(a, b));
    return *reinterpret_cast<unsigned int*>(&h);
}
// Branchless exact ELU: max(x,0) + (exp(min(x,0)) - 1)
__device__ __forceinline__ float elu(float x) {
    return fmaxf(x, 0.f) + (__expf(fminf(x, 0.f)) - 1.f);
}

// ---------------------------------------------------------------------------
// Kernel 1 (fine-sliced): blocks [0,288) = 16-row MFMA GEMM tiles producing
// zl' (32 blk) / zt' (256 blk); block 288 = wcomb_t.
// ---------------------------------------------------------------------------
__global__ __launch_bounds__(256) void k_pre(
    const float* __restrict__ hl,
    const float* __restrict__ ht,
    const float* __restrict__ W1,
    const float* __restrict__ b1,
    const float* __restrict__ gamma_,
    const float* __restrict__ beta_,
    const float* __restrict__ rmean,
    const float* __restrict__ rvar,
    const float* __restrict__ Wpi,
    const float* __restrict__ Wsig,
    const float* __restrict__ Wmu,
    unsigned short* __restrict__ zl,
    unsigned short* __restrict__ zt,
    unsigned short* __restrict__ wcomb_t)
{
    const int blk = blockIdx.x;
    const int tid = threadIdx.x;
    const int lane = tid & 63;
    const int wave = tid >> 6;
    const int m    = lane & 15;
    const int quad = lane >> 4;

    if (blk < 288) {
        const bool is_l = (blk < 32);
        const int rbase = is_l ? blk * 16 : (blk - 32) * 16;
        const float* A  = is_l ? hl : ht;
        const float* Wx = W1 + (is_l ? 0 : (size_t)CF * HD);   // [128 c][128 h]
        unsigned short* Z = is_l ? zl : zt;
        const int n0 = wave * 32 + m;

        floatx4 acc[2];
        acc[0] = (floatx4){0.f, 0.f, 0.f, 0.f};
        acc[1] = (floatx4){0.f, 0.f, 0.f, 0.f};

        #pragma unroll
        for (int kb = 0; kb < 4; ++kb) {
            const int k0 = kb * 32 + quad * 8;
            const float* ap = A + (size_t)(rbase + m) * CF + k0;
            const float4 f0 = *(const float4*)ap;
            const float4 f1 = *(const float4*)(ap + 4);
            U8 t;
            t.u[0] = pk2bf(f0.x, f0.y);
            t.u[1] = pk2bf(f0.z, f0.w);
            t.u[2] = pk2bf(f1.x, f1.y);
            t.u[3] = pk2bf(f1.z, f1.w);
            const short8 a = t.s8;

            short8 bf[2];
            #pragma unroll
            for (int nt = 0; nt < 2; ++nt) {
                const int n = n0 + nt * 16;
                float w[8];
                #pragma unroll
                for (int j = 0; j < 8; ++j)
                    w[j] = Wx[(size_t)(k0 + j) * HD + n];
                U8 tt;
                #pragma unroll
                for (int j = 0; j < 4; ++j) tt.u[j] = pk2bf(w[2*j], w[2*j+1]);
                bf[nt] = tt.s8;
            }
            #pragma unroll
            for (int nt = 0; nt < 2; ++nt)
                acc[nt] = __builtin_amdgcn_mfma_f32_16x16x32_bf16(a, bf[nt], acc[nt], 0, 0, 0);
        }

        #pragma unroll
        for (int nt = 0; nt < 2; ++nt) {
            const int col = n0 + nt * 16;
            const float s   = gamma_[col] * rsqrtf(rvar[col] + 1e-4f);
            const float off = is_l ? 0.f : ((b1[col] - rmean[col]) * s + beta_[col]);
            #pragma unroll
            for (int r = 0; r < 4; ++r) {
                const int row = rbase + quad * 4 + r;
                Z[(size_t)row * HD + col] = f2bf(acc[nt][r] * s + off);
            }
        }
    } else {
        // wcomb_t[n][k]: n 0-9 = Wpi col, 10-19 = Wsig, 20-29 = Wmu, 30-31 = 0
        for (int i = tid; i < 32 * HD; i += 256) {
            const int n = i >> 7, k = i & 127;
            float v = 0.f;
            if (n < 10)      v = Wpi [k * NK + n];
            else if (n < 20) v = Wsig[k * NK + (n - 10)];
            else if (n < 30) v = Wmu [k * NK + (n - 20)];
            wcomb_t[i] = f2bf(v);
        }
    }
}

// ---------------------------------------------------------------------------
// Kernel 2: blocks [0,2048) = one per (b, l, chunk-of-128-t) — R7-validated
// body, now at __launch_bounds__(256,8): R9 proved this body compiles to
// 64 VGPR, so 8 blocks/CU (LDS 17.4KB*8=139KB<160KB) => 2x TLP vs R7.
// Blocks [2048,2052) = atom_types MFMA; [2052,2060) = bond_types MFMA.
// ---------------------------------------------------------------------------
__global__ __launch_bounds__(256, 8) void k_main(
    const unsigned short* __restrict__ zl,
    const unsigned short* __restrict__ zt,
    const unsigned short* __restrict__ wcomb_t,
    const float* __restrict__ bpi,
    const float* __restrict__ bsig,
    const float* __restrict__ bmu,
    const float* __restrict__ hlpos,
    const float* __restrict__ htpos,
    const float* __restrict__ hl,
    const int*   __restrict__ eidx,
    const float* __restrict__ Wat,
    const float* __restrict__ bat,
    const float* __restrict__ Wbd,
    const float* __restrict__ bbd,
    float* __restrict__ out)
{
    __shared__ float Dl[128 * 34];   // 17408 B, stride 34 => <=2-way banks
    __shared__ float biass[32];
    __shared__ float pls[3];

    const int tid  = threadIdx.x;
    const int blk  = blockIdx.x;
    const int lane = tid & 63;
    const int wave = tid >> 6;
    const int m    = lane & 15;
    const int quad = lane >> 4;

    if (blk >= 2048) {
        const int ab = blk - 2048;
        if (ab < 4) {
            // ---- atom_types: rows ab*128 + wave*32 .. +31 ----
            const int rbase = ab * 128 + wave * 32;
            floatx4 acc[2][2];
            #pragma unroll
            for (int i = 0; i < 2; ++i)
                #pragma unroll
                for (int j = 0; j < 2; ++j)
                    acc[i][j] = (floatx4){0.f, 0.f, 0.f, 0.f};
            #pragma unroll
            for (int kb = 0; kb < 4; ++kb) {
                const int k0 = kb * 32 + quad * 8;
                short8 a[2];
                #pragma unroll
                for (int mt = 0; mt < 2; ++mt) {
                    const float* ap = hl + (size_t)(rbase + mt * 16 + m) * CF + k0;
                    const float4 f0 = *(const float4*)ap;
                    const float4 f1 = *(const float4*)(ap + 4);
                    U8 t;
                    t.u[0] = pk2bf(f0.x, f0.y);
                    t.u[1] = pk2bf(f0.z, f0.w);
                    t.u[2] = pk2bf(f1.x, f1.y);
                    t.u[3] = pk2bf(f1.z, f1.w);
                    a[mt] = t.s8;
                }
                short8 bf[2];
                #pragma unroll
                for (int nt = 0; nt < 2; ++nt) {
                    const int n = nt * 16 + m;
                    const int nc = (n < 28) ? n : 0;
                    #pragma unroll
                    for (int j = 0; j < 8; ++j) {
                        const float w = Wat[(size_t)(k0 + j) * 28 + nc];
                        bf[nt][j] = (short)f2bf((n < 28) ? w : 0.f);
                    }
                }
                #pragma unroll
                for (int mt = 0; mt < 2; ++mt)
                    #pragma unroll
                    for (int nt = 0; nt < 2; ++nt)
                        acc[mt][nt] = __builtin_amdgcn_mfma_f32_16x16x32_bf16(a[mt], bf[nt], acc[mt][nt], 0, 0, 0);
            }
            #pragma unroll
            for (int nt = 0; nt < 2; ++nt) {
                const int col = nt * 16 + m;
                if (col < 28) {
                    const float bias = bat[col];
                    #pragma unroll
                    for (int mt = 0; mt < 2; ++mt)
                        #pragma unroll
                        for (int r = 0; r < 4; ++r) {
                            const int row = rbase + mt * 16 + quad * 4 + r;
                            out[AT_OFF + (size_t)row * 28 + col] = acc[mt][nt][r] + bias;
                        }
                }
            }
        } else {
            // ---- bond_types: rows (ab-4)*128 + wave*32 .. +31, K=256 ----
            const int rbase = (ab - 4) * 128 + wave * 32;
            const int e0 = rbase + m, e1 = rbase + 16 + m;
            const int s00 = eidx[e0], s01 = eidx[NE + e0];
            const int s10 = eidx[e1], s11 = eidx[NE + e1];
            floatx4 acc[2];
            acc[0] = (floatx4){0.f, 0.f, 0.f, 0.f};
            acc[1] = (floatx4){0.f, 0.f, 0.f, 0.f};
            const int nc = (m < 6) ? m : 0;
            #pragma unroll
            for (int kb = 0; kb < 8; ++kb) {
                const int k0 = kb * 32 + quad * 8;
                const bool lo = (k0 < 128);
                const int off = lo ? k0 : (k0 - 128);
                short8 a[2];
                #pragma unroll
                for (int mt = 0; mt < 2; ++mt) {
                    const int src = lo ? (mt ? s10 : s00) : (mt ? s11 : s01);
                    const float* ap = hl + (size_t)src * CF + off;
                    const float4 f0 = *(const float4*)ap;
                    const float4 f1 = *(const float4*)(ap + 4);
                    U8 t;
                    t.u[0] = pk2bf(f0.x, f0.y);
                    t.u[1] = pk2bf(f0.z, f0.w);
                    t.u[2] = pk2bf(f1.x, f1.y);
                    t.u[3] = pk2bf(f1.z, f1.w);
                    a[mt] = t.s8;
                }
                short8 bf;
                #pragma unroll
                for (int j = 0; j < 8; ++j) {
                    const float w = Wbd[(size_t)(k0 + j) * 6 + nc];
                    bf[j] = (short)f2bf((m < 6) ? w : 0.f);
                }
                acc[0] = __builtin_amdgcn_mfma_f32_16x16x32_bf16(a[0], bf, acc[0], 0, 0, 0);
                acc[1] = __builtin_amdgcn_mfma_f32_16x16x32_bf16(a[1], bf, acc[1], 0, 0, 0);
            }
            if (m < 6) {
                const float bias = bbd[m];
                #pragma unroll
                for (int mt = 0; mt < 2; ++mt)
                    #pragma unroll
                    for (int r = 0; r < 4; ++r) {
                        const int row = rbase + mt * 16 + quad * 4 + r;
                        out[BD_OFF + (size_t)row * 6 + m] = acc[mt][r] + bias;
                    }
            }
        }
        return;
    }

    const int b  = blk >> 8;
    const int l  = (blk >> 2) & 63;
    const int ch = blk & 3;

    if (tid < 32) {
        float v = 0.f;
        if (tid < 10)      v = bpi[tid];
        else if (tid < 20) v = bsig[tid - 10];
        else if (tid < 30) v = bmu[tid - 20];
        biass[tid] = v;
    } else if (tid < 35) {
        pls[tid - 32] = hlpos[(size_t)(b * NL + l) * 3 + (tid - 32)];
    }

    // B fragments: single 16B loads from transposed head weights
    short8 bfrag[2][4];
    #pragma unroll
    for (int nt = 0; nt < 2; ++nt)
        #pragma unroll
        for (int kb = 0; kb < 4; ++kb)
            bfrag[nt][kb] = *(const short8*)(wcomb_t + (size_t)(nt * 16 + m) * HD + kb * 32 + quad * 8);

    // ---- stage A: direct A-frag compute + MFMA ----
    const unsigned short* zlr = zl + (size_t)(b * NL + l) * HD;
    const unsigned short* ztb = zt + (size_t)(b * NT + ch * 128) * HD;

    floatx4 acc[2][2];
    #pragma unroll
    for (int i = 0; i < 2; ++i)
        #pragma unroll
        for (int j = 0; j < 2; ++j)
            acc[i][j] = (floatx4){0.f, 0.f, 0.f, 0.f};

    #pragma unroll
    for (int kb = 0; kb < 4; ++kb) {
        const int k0 = kb * 32 + quad * 8;
        const short8 zlv = *(const short8*)(zlr + k0);
        float zf[8];
        #pragma unroll
        for (int j = 0; j < 8; ++j) zf[j] = bf2f((unsigned short)zlv[j]);

        short8 a[2];
        #pragma unroll
        for (int mt = 0; mt < 2; ++mt) {
            const int row = wave * 32 + mt * 16 + m;
            const short8 ztv = *(const short8*)(ztb + (size_t)row * HD + k0);
            float e[8];
            #pragma unroll
            for (int j = 0; j < 8; ++j)
                e[j] = elu(zf[j] + bf2f((unsigned short)ztv[j]));
            U8 t;
            #pragma unroll
            for (int j = 0; j < 4; ++j) t.u[j] = pk2bf(e[2*j], e[2*j+1]);
            a[mt] = t.s8;
        }
        #pragma unroll
        for (int mt = 0; mt < 2; ++mt)
            #pragma unroll
            for (int nt = 0; nt < 2; ++nt)
                acc[mt][nt] = __builtin_amdgcn_mfma_f32_16x16x32_bf16(a[mt], bfrag[nt][kb], acc[mt][nt], 0, 0, 0);
    }

    // D: col = lane&15, row = quad*4 + r   [validated R3/R4]
    #pragma unroll
    for (int mt = 0; mt < 2; ++mt)
        #pragma unroll
        for (int nt = 0; nt < 2; ++nt)
            #pragma unroll
            for (int r = 0; r < 4; ++r) {
                const int row = wave * 32 + mt * 16 + quad * 4 + r;
                const int col = nt * 16 + m;
                Dl[row * 34 + col] = acc[mt][nt][r];
            }
    __syncthreads();

    // ---- stage B: epilogues (fp32 stores) ----
    const size_t gp = ((size_t)(b * NL + l)) * NT + ch * 128 + (tid & 127);
    if (tid < 128) {
        const int p = tid;
        float v[10];
        float mx = -1e30f;
        #pragma unroll
        for (int n = 0; n < 10; ++n) {
            v[n] = Dl[p * 34 + n] + biass[n];
            mx = fmaxf(mx, v[n]);
        }
        float s = 0.f;
        #pragma unroll
        for (int n = 0; n < 10; ++n) { v[n] = __expf(v[n] - mx); s += v[n]; }
        const float inv = 1.f / s;
        floatx2* po = (floatx2*)(out + PI_OFF + gp * 10);
        #pragma unroll
        for (int n = 0; n < 5; ++n) po[n] = (floatx2){v[2*n] * inv, v[2*n+1] * inv};
    } else {
        const int p = tid - 128;
        float sg[10], mv[10];
        #pragma unroll
        for (int n = 0; n < 10; ++n) {
            sg[n] = elu(Dl[p * 34 + 10 + n] + biass[10 + n]) + 1.1f;
            mv[n] = elu(Dl[p * 34 + 20 + n] + biass[20 + n]) + 1.0f;
        }
        floatx2* ps = (floatx2*)(out + SIG_OFF + gp * 10);
        floatx2* pm = (floatx2*)(out + MU_OFF  + gp * 10);
        #pragma unroll
        for (int n = 0; n < 5; ++n) {
            ps[n] = (floatx2){sg[2*n], sg[2*n+1]};
            pm[n] = (floatx2){mv[2*n], mv[2*n+1]};
        }
        const int t = ch * 128 + p;
        const size_t pb = (size_t)(b * NT + t) * 3;
        const float dx = pls[0] - htpos[pb + 0];
        const float dy = pls[1] - htpos[pb + 1];
        const float dz = pls[2] - htpos[pb + 2];
        out[DIST_OFF + gp] = sqrtf(dx * dx + dy * dy + dz * dz);
        out[CB_OFF + gp]   = (float)b;
    }
}

// ---------------------------------------------------------------------------
extern "C" void kernel_launch(void* const* d_in, const int* in_sizes, int n_in,
                              void* d_out, int out_size, void* d_ws, size_t ws_size,
                              hipStream_t stream)
{
    const float* hl     = (const float*)d_in[0];
    const float* ht     = (const float*)d_in[1];
    const float* hlpos  = (const float*)d_in[2];
    const float* htpos  = (const float*)d_in[3];
    const int*   eidx   = (const int*)d_in[4];
    const float* W1     = (const float*)d_in[5];
    const float* b1     = (const float*)d_in[6];
    const float* gamma_ = (const float*)d_in[7];
    const float* beta_  = (const float*)d_in[8];
    const float* rmean  = (const float*)d_in[9];
    const float* rvar   = (const float*)d_in[10];
    const float* Wpi    = (const float*)d_in[11];
    const float* bpi    = (const float*)d_in[12];
    const float* Wsig   = (const float*)d_in[13];
    const float* bsig   = (const float*)d_in[14];
    const float* Wmu    = (const float*)d_in[15];
    const float* bmu    = (const float*)d_in[16];
    const float* Wat    = (const float*)d_in[17];
    const float* bat    = (const float*)d_in[18];
    const float* Wbd    = (const float*)d_in[19];
    const float* bbd    = (const float*)d_in[20];

    float* out = (float*)d_out;
    unsigned short* ws  = (unsigned short*)d_ws;
    unsigned short* zl      = ws;                          // 512*128 bf16
    unsigned short* zt      = ws + 512 * 128;              // 4096*128 bf16
    unsigned short* wcomb_t = ws + 512 * 128 + 4096 * 128; // 32*128 bf16

    k_pre<<<289, 256, 0, stream>>>(hl, ht, W1, b1, gamma_, beta_, rmean, rvar,
                                   Wpi, Wsig, Wmu, zl, zt, wcomb_t);
    k_main<<<2060, 256, 0, stream>>>(zl, zt, wcomb_t, bpi, bsig, bmu, hlpos, htpos,
                                     hl, eidx, Wat, bat, Wbd, bbd, out);
}